// Round 1
// baseline (1617.154 us; speedup 1.0000x reference)
//
#include <hip/hip_runtime.h>
#include <hip/hip_fp16.h>

#define N_NODES 10000
#define N_EDGES 40000
#define N_GRAPH 64
#define KKREAL  262144          // 4096 * 64
#define KKTOT   262272          // + 128 (virtual k=4096 bias rank + zero pad)
#define BROW    KKTOT           // B' row stride in halves

typedef _Float16 half8_t __attribute__((ext_vector_type(8)));
typedef float    floatx4 __attribute__((ext_vector_type(4)));

// ---------------- prep: B'[o][k*64+i] = w2_1[k][i*64+o]  (f16), bias rank at k=4096
__global__ void prep_B(const float* __restrict__ w2, const float* __restrict__ b2,
                       _Float16* __restrict__ Bws) {
  int kk = blockIdx.x * blockDim.x + threadIdx.x;
  if (kk >= KKTOT) return;
  int k = kk >> 6, i = kk & 63;
  #pragma unroll 4
  for (int o = 0; o < 64; ++o) {
    float v;
    if (k < 4096)       v = w2[k * 4096 + i * 64 + o];
    else if (k == 4096) v = b2[i * 64 + o];
    else                v = 0.f;
    Bws[(size_t)o * BROW + kk] = (_Float16)v;
  }
}

// ---------------- layer 0: per-edge MLP (in_dim=1) + scatter-sum + degree count
__global__ void layer0_edge(const float* __restrict__ node_ids,
                            const int* __restrict__ ei,
                            const float* __restrict__ ea,
                            const float* __restrict__ w1, const float* __restrict__ b1,
                            const float* __restrict__ w2, const float* __restrict__ b2,
                            float* __restrict__ agg0, float* __restrict__ cnt) {
  __shared__ float w1s[256], b1s[64], w2s[4096], b2s[64], zb[4][64];
  int t = threadIdx.x;
  for (int idx = t; idx < 4096; idx += 256) w2s[idx] = w2[idx];
  if (t < 256) w1s[t] = w1[t];
  if (t < 64) { b1s[t] = b1[t]; b2s[t] = b2[t]; }
  __syncthreads();
  int w = t >> 6, l = t & 63;
  int gw = blockIdx.x * 4 + w;
  int nw = gridDim.x * 4;
  for (int e = gw; e < N_EDGES; e += nw) {
    float a0 = ea[e * 4 + 0], a1 = ea[e * 4 + 1], a2 = ea[e * 4 + 2], a3 = ea[e * 4 + 3];
    float z = a0 * w1s[l] + a1 * w1s[64 + l] + a2 * w1s[128 + l] + a3 * w1s[192 + l] + b1s[l];
    zb[w][l] = fmaxf(z, 0.f);
    asm volatile("s_waitcnt lgkmcnt(0)" ::: "memory");
    __builtin_amdgcn_sched_barrier(0);
    float h = b2s[l];
    #pragma unroll
    for (int k = 0; k < 64; ++k) h += zb[w][k] * w2s[k * 64 + l];
    int src = ei[e], dst = ei[N_EDGES + e];
    float msg = node_ids[src] * h;
    atomicAdd(&agg0[dst * 64 + l], msg);
    if (l == 0) atomicAdd(&cnt[dst], 1.0f);
  }
}

// ---------------- node update 0: x1 = relu(agg0/cnt + node_ids*root0 + bias0); pool counts
__global__ void node0(const float* __restrict__ node_ids, const int* __restrict__ batch,
                      const float* __restrict__ agg0, const float* __restrict__ cnt,
                      const float* __restrict__ root0, const float* __restrict__ bias0,
                      float* __restrict__ x1, float* __restrict__ pcnt) {
  int gid = blockIdx.x * 256 + threadIdx.x;
  if (gid >= N_NODES * 64) return;
  int n = gid >> 6, o = gid & 63;
  float c = fmaxf(cnt[n], 1.f);
  float v = agg0[gid] / c + node_ids[n] * root0[o] + bias0[o];
  x1[gid] = fmaxf(v, 0.f);
  if (o == 0) atomicAdd(&pcnt[batch[n]], 1.0f);
}

// ---------------- layer 1 fused: msg[e,o] = sum_kk (z_e[k]*x_e[i]) * B'[kk,o], scatter to agg1
// grid = 157 edge-blocks * 8 K-slices; block = 256 thr (4 waves), block tile [256 edges x 64 o]
__launch_bounds__(256, 2)
__global__ void fused_edge_gemm(const int* __restrict__ ei,
                                const float* __restrict__ ea,
                                const float* __restrict__ x1,
                                const float* __restrict__ w1, const float* __restrict__ b1,
                                const _Float16* __restrict__ Bws,
                                float* __restrict__ agg1) {
  __shared__ __attribute__((aligned(16))) _Float16 Bl[2][64 * 128];
  __shared__ float w1s[4 * 512], b1s[512];
  int t = threadIdx.x;
  int ks = blockIdx.x & 7;
  int eb = blockIdx.x >> 3;
  int e0 = eb * 256;
  int w = t >> 6, l = t & 63;

  int kb = ks * 512;                       // real-k base of this slice
  for (int j = t; j < 512; j += 256) {
    #pragma unroll
    for (int d = 0; d < 4; ++d) w1s[d * 512 + j] = w1[d * 4096 + kb + j];
    b1s[j] = b1[kb + j];
  }

  // per-lane registers: x fragments (16 i-values per edge, 4 edges) + edge_attr
  int ibase = (l >> 4) * 8;
  __half2 xh[4][8];
  float   eav[4][4];
  #pragma unroll
  for (int m = 0; m < 4; ++m) {
    int e = e0 + w * 64 + m * 16 + (l & 15);
    if (e < N_EDGES) {
      int src = ei[e];
      const float* xp = x1 + src * 64;
      #pragma unroll
      for (int h = 0; h < 2; ++h) {
        float4 f0 = *(const float4*)(xp + ibase + h * 32);
        float4 f1 = *(const float4*)(xp + ibase + h * 32 + 4);
        xh[m][h * 4 + 0] = __floats2half2_rn(f0.x, f0.y);
        xh[m][h * 4 + 1] = __floats2half2_rn(f0.z, f0.w);
        xh[m][h * 4 + 2] = __floats2half2_rn(f1.x, f1.y);
        xh[m][h * 4 + 3] = __floats2half2_rn(f1.z, f1.w);
      }
      float4 av = *(const float4*)(ea + e * 4);
      eav[m][0] = av.x; eav[m][1] = av.y; eav[m][2] = av.z; eav[m][3] = av.w;
    } else {
      #pragma unroll
      for (int p = 0; p < 8; ++p) xh[m][p] = __floats2half2_rn(0.f, 0.f);
      eav[m][0] = eav[m][1] = eav[m][2] = eav[m][3] = 0.f;
    }
  }

  floatx4 zero4 = {0.f, 0.f, 0.f, 0.f};
  floatx4 acc[4][4];
  #pragma unroll
  for (int m = 0; m < 4; ++m)
    #pragma unroll
    for (int n = 0; n < 4; ++n) acc[m][n] = zero4;

  int nchunk = (ks == 7) ? 257 : 256;
  long long sbase = (long long)ks * 32768;

  // staging assignment: thread t covers B' row r=t>>2, 16B-chunks cc = (t&3)+4j
  int r_row = t >> 2;
  int c4 = t & 3;
  const _Float16* browp = Bws + (size_t)r_row * BROW;

  auto stage_load = [&](int c, uint4* regs) {
    long long kk0 = sbase + (long long)c * 128;
    #pragma unroll
    for (int j = 0; j < 4; ++j) {
      int cc = c4 + j * 4;
      regs[j] = *(const uint4*)(browp + kk0 + cc * 8);
    }
  };
  auto stage_write = [&](int buf, uint4* regs) {
    #pragma unroll
    for (int j = 0; j < 4; ++j) {
      int cc = c4 + j * 4;
      int byteoff = r_row * 256 + ((cc ^ (r_row & 7)) << 4);   // XOR swizzle
      *(uint4*)((char*)&Bl[buf][0] + byteoff) = regs[j];
    }
  };

  uint4 st[4];
  stage_load(0, st);
  stage_write(0, st);
  __syncthreads();

  int cur = 0;
  for (int c = 0; c < nchunk; ++c) {
    bool more = (c + 1 < nchunk);
    uint4 nx[4];
    if (more) stage_load(c + 1, nx);       // issue-early (T14); write-late below

    // z for this chunk's two real-k values (or bias rank)
    float zf[4][2];
    if (c < 256) {
      int klocal = 2 * c;
      #pragma unroll
      for (int m = 0; m < 4; ++m) {
        #pragma unroll
        for (int q = 0; q < 2; ++q) {
          int kl = klocal + q;
          float z = eav[m][0] * w1s[kl] + eav[m][1] * w1s[512 + kl]
                  + eav[m][2] * w1s[1024 + kl] + eav[m][3] * w1s[1536 + kl] + b1s[kl];
          zf[m][q] = fmaxf(z, 0.f);
        }
      }
    } else {  // bias chunk: k=4096 -> z=1 (picks up b2 term), k=4097 -> 0
      #pragma unroll
      for (int m = 0; m < 4; ++m) { zf[m][0] = 1.f; zf[m][1] = 0.f; }
    }
    __half2 zh[4][2];
    #pragma unroll
    for (int m = 0; m < 4; ++m) {
      zh[m][0] = __float2half2_rn(zf[m][0]);
      zh[m][1] = __float2half2_rn(zf[m][1]);
    }

    #pragma unroll
    for (int s = 0; s < 4; ++s) {
      half8_t bf[4];
      #pragma unroll
      for (int n = 0; n < 4; ++n) {
        int o = n * 16 + (l & 15);
        int cc = s * 4 + (l >> 4);
        int byteoff = o * 256 + ((cc ^ (o & 7)) << 4);
        bf[n] = *(const half8_t*)((const char*)&Bl[cur][0] + byteoff);
      }
      #pragma unroll
      for (int m = 0; m < 4; ++m) {
        __half2 zd = zh[m][s >> 1];
        union { half8_t v; __half2 p[4]; } af;
        #pragma unroll
        for (int p = 0; p < 4; ++p) af.p[p] = __hmul2(xh[m][(s & 1) * 4 + p], zd);
        #pragma unroll
        for (int n = 0; n < 4; ++n)
          acc[m][n] = __builtin_amdgcn_mfma_f32_16x16x32_f16(af.v, bf[n], acc[m][n], 0, 0, 0);
      }
    }

    if (more) stage_write(cur ^ 1, nx);
    __syncthreads();
    cur ^= 1;
  }

  // epilogue: scatter partial msg into agg1[dst] (C/D layout: col=lane&15, row=(lane>>4)*4+reg)
  #pragma unroll
  for (int m = 0; m < 4; ++m) {
    #pragma unroll
    for (int r = 0; r < 4; ++r) {
      int e = e0 + w * 64 + m * 16 + (l >> 4) * 4 + r;
      if (e < N_EDGES) {
        int dst = ei[N_EDGES + e];
        float* ap = agg1 + dst * 64 + (l & 15);
        #pragma unroll
        for (int n = 0; n < 4; ++n) atomicAdd(ap + n * 16, acc[m][n][r]);
      }
    }
  }
}

// ---------------- node update 1 + global mean pool accumulate
__global__ void node1_pool(const int* __restrict__ batch, const float* __restrict__ x1,
                           const float* __restrict__ agg1, const float* __restrict__ cnt,
                           const float* __restrict__ root1, const float* __restrict__ bias1,
                           float* __restrict__ psum) {
  __shared__ float rt[4096];
  int t = threadIdx.x;
  for (int idx = t; idx < 4096; idx += 256) rt[idx] = root1[idx];
  __syncthreads();
  int w = t >> 6, l = t & 63;
  int n = blockIdx.x * 4 + w;
  if (n >= N_NODES) return;
  float c = fmaxf(cnt[n], 1.f);
  float acc = agg1[n * 64 + l] / c + bias1[l];
  const float* xp = x1 + n * 64;
  #pragma unroll
  for (int i4 = 0; i4 < 16; ++i4) {
    float4 xv = *(const float4*)(xp + i4 * 4);
    acc += xv.x * rt[(i4 * 4 + 0) * 64 + l] + xv.y * rt[(i4 * 4 + 1) * 64 + l]
         + xv.z * rt[(i4 * 4 + 2) * 64 + l] + xv.w * rt[(i4 * 4 + 3) * 64 + l];
  }
  acc = fmaxf(acc, 0.f);
  atomicAdd(&psum[batch[n] * 64 + l], acc);
}

// ---------------- classifier head: one wave per graph
__global__ void classifier(const float* __restrict__ psum, const float* __restrict__ pcnt,
                           const float* __restrict__ wc1, const float* __restrict__ bc1,
                           const float* __restrict__ wc2, const float* __restrict__ bc2,
                           float* __restrict__ out) {
  __shared__ float hb[64];
  int g = blockIdx.x, j = threadIdx.x;
  float c = fmaxf(pcnt[g], 1.f);
  float h = bc1[j];
  const float* pp = psum + g * 64;
  #pragma unroll
  for (int i4 = 0; i4 < 16; ++i4) {
    float4 pv = *(const float4*)(pp + i4 * 4);
    h += (pv.x / c) * wc1[(i4 * 4 + 0) * 64 + j] + (pv.y / c) * wc1[(i4 * 4 + 1) * 64 + j]
       + (pv.z / c) * wc1[(i4 * 4 + 2) * 64 + j] + (pv.w / c) * wc1[(i4 * 4 + 3) * 64 + j];
  }
  hb[j] = fmaxf(h, 0.f);
  __syncthreads();
  if (j < 4) {
    float o = bc2[j];
    #pragma unroll
    for (int k = 0; k < 64; ++k) o += hb[k] * wc2[k * 4 + j];
    out[g * 4 + j] = o;
  }
}

extern "C" void kernel_launch(void* const* d_in, const int* in_sizes, int n_in,
                              void* d_out, int out_size, void* d_ws, size_t ws_size,
                              hipStream_t stream) {
  const float* node_ids = (const float*)d_in[0];
  const int*   ei       = (const int*)d_in[1];
  const float* ea       = (const float*)d_in[2];
  const int*   batch    = (const int*)d_in[3];
  const float* w1_0 = (const float*)d_in[4];
  const float* b1_0 = (const float*)d_in[5];
  const float* w2_0 = (const float*)d_in[6];
  const float* b2_0 = (const float*)d_in[7];
  const float* root0 = (const float*)d_in[8];
  const float* bias0 = (const float*)d_in[9];
  const float* w1_1 = (const float*)d_in[10];
  const float* b1_1 = (const float*)d_in[11];
  const float* w2_1 = (const float*)d_in[12];
  const float* b2_1 = (const float*)d_in[13];
  const float* root1 = (const float*)d_in[14];
  const float* bias1 = (const float*)d_in[15];
  const float* wc1 = (const float*)d_in[16];
  const float* bc1 = (const float*)d_in[17];
  const float* wc2 = (const float*)d_in[18];
  const float* bc2 = (const float*)d_in[19];
  float* out = (float*)d_out;

  char* ws = (char*)d_ws;
  _Float16* Bws = (_Float16*)ws;                       // 33,570,816 B
  float* x1   = (float*)(ws + 33570816);               //  2,560,000 B
  float* agg0 = (float*)(ws + 36130816);               //  2,560,000 B (zeroed)
  float* agg1 = (float*)(ws + 38690816);               //  2,560,000 B (zeroed)
  float* cnt  = (float*)(ws + 41250816);               //     40,000 B (zeroed)
  float* psum = (float*)(ws + 41290816);               //     16,384 B (zeroed)
  float* pcnt = (float*)(ws + 41307200);               //        256 B (zeroed)

  hipMemsetAsync(agg0, 0, 2560000 + 2560000 + 40000 + 16384 + 256, stream);

  prep_B<<<(KKTOT + 255) / 256, 256, 0, stream>>>(w2_1, b2_1, Bws);
  layer0_edge<<<512, 256, 0, stream>>>(node_ids, ei, ea, w1_0, b1_0, w2_0, b2_0, agg0, cnt);
  node0<<<(N_NODES * 64 + 255) / 256, 256, 0, stream>>>(node_ids, batch, agg0, cnt, root0, bias0, x1, pcnt);
  fused_edge_gemm<<<157 * 8, 256, 0, stream>>>(ei, ea, x1, w1_1, b1_1, Bws, agg1);
  node1_pool<<<(N_NODES + 3) / 4, 256, 0, stream>>>(batch, x1, agg1, cnt, root1, bias1, psum);
  classifier<<<N_GRAPH, 64, 0, stream>>>(psum, pcnt, wc1, bc1, wc2, bc2, out);
}

// Round 3
// 1596.028 us; speedup vs baseline: 1.0132x; 1.0132x over previous
//
#include <hip/hip_runtime.h>
#include <hip/hip_fp16.h>

#define N_NODES 10000
#define N_EDGES 40000
#define N_GRAPH 64
#define KKREAL  262144          // 4096 * 64
#define KKTOT   262272          // + 128 (virtual k=4096 bias rank + zero pad)
#define BROW    KKTOT           // B' row stride in halves
#define EPAD    40192           // 157 * 256 padded edge count
#define PSLICE  (EPAD * 64)     // floats per partial slice

typedef _Float16 half8_t __attribute__((ext_vector_type(8)));
typedef float    floatx4 __attribute__((ext_vector_type(4)));

// ---------------- prep: B'[o][k*64+i] = w2_1[k][i*64+o]  (f16), bias rank at k=4096
__global__ void prep_B(const float* __restrict__ w2, const float* __restrict__ b2,
                       _Float16* __restrict__ Bws) {
  int kk = blockIdx.x * blockDim.x + threadIdx.x;
  if (kk >= KKTOT) return;
  int k = kk >> 6, i = kk & 63;
  #pragma unroll 4
  for (int o = 0; o < 64; ++o) {
    float v;
    if (k < 4096)       v = w2[k * 4096 + i * 64 + o];
    else if (k == 4096) v = b2[i * 64 + o];
    else                v = 0.f;
    Bws[(size_t)o * BROW + kk] = (_Float16)v;
  }
}

// ---------------- layer 0: per-edge MLP (in_dim=1) + scatter-sum + degree count
__global__ void layer0_edge(const float* __restrict__ node_ids,
                            const int* __restrict__ ei,
                            const float* __restrict__ ea,
                            const float* __restrict__ w1, const float* __restrict__ b1,
                            const float* __restrict__ w2, const float* __restrict__ b2,
                            float* __restrict__ agg0, float* __restrict__ cnt) {
  __shared__ float w1s[256], b1s[64], w2s[4096], b2s[64], zb[4][64];
  int t = threadIdx.x;
  for (int idx = t; idx < 4096; idx += 256) w2s[idx] = w2[idx];
  if (t < 256) w1s[t] = w1[t];
  if (t < 64) { b1s[t] = b1[t]; b2s[t] = b2[t]; }
  __syncthreads();
  int w = t >> 6, l = t & 63;
  int gw = blockIdx.x * 4 + w;
  int nw = gridDim.x * 4;
  for (int e = gw; e < N_EDGES; e += nw) {
    float a0 = ea[e * 4 + 0], a1 = ea[e * 4 + 1], a2 = ea[e * 4 + 2], a3 = ea[e * 4 + 3];
    float z = a0 * w1s[l] + a1 * w1s[64 + l] + a2 * w1s[128 + l] + a3 * w1s[192 + l] + b1s[l];
    zb[w][l] = fmaxf(z, 0.f);
    asm volatile("s_waitcnt lgkmcnt(0)" ::: "memory");
    __builtin_amdgcn_sched_barrier(0);
    float h = b2s[l];
    #pragma unroll
    for (int k = 0; k < 64; ++k) h += zb[w][k] * w2s[k * 64 + l];
    int src = ei[e], dst = ei[N_EDGES + e];
    float msg = node_ids[src] * h;
    atomicAdd(&agg0[dst * 64 + l], msg);
    if (l == 0) atomicAdd(&cnt[dst], 1.0f);
  }
}

// ---------------- node update 0: x1 = relu(agg0/cnt + node_ids*root0 + bias0); pool counts
__global__ void node0(const float* __restrict__ node_ids, const int* __restrict__ batch,
                      const float* __restrict__ agg0, const float* __restrict__ cnt,
                      const float* __restrict__ root0, const float* __restrict__ bias0,
                      float* __restrict__ x1, float* __restrict__ pcnt) {
  int gid = blockIdx.x * 256 + threadIdx.x;
  if (gid >= N_NODES * 64) return;
  int n = gid >> 6, o = gid & 63;
  float c = fmaxf(cnt[n], 1.f);
  float v = agg0[gid] / c + node_ids[n] * root0[o] + bias0[o];
  x1[gid] = fmaxf(v, 0.f);
  if (o == 0) atomicAdd(&pcnt[batch[n]], 1.0f);
}

// ---------------- layer 1 fused: msg[e,o] = sum_kk (z_e[k]*x_e[i]) * B'[kk,o]
// grid = 157 edge-blocks * 8 K-slices; block = 256 thr (4 waves), tile [256 edges x 64 o]
// PART=1: write exclusive f32 partials P8[ks][e][o]; PART=0: atomicAdd into agg1
template <bool PART>
__launch_bounds__(256, 3)
__global__ void fused_edge_gemm(const int* __restrict__ ei,
                                const float* __restrict__ ea,
                                const float* __restrict__ x1,
                                const float* __restrict__ w1, const float* __restrict__ b1,
                                const _Float16* __restrict__ Bws,
                                float* __restrict__ outbuf) {
  __shared__ __attribute__((aligned(16))) _Float16 Bl[2][64 * 128];
  __shared__ __half2 w1p[4 * 256];   // (w1[d][kb+2c], w1[d][kb+2c+1])
  __shared__ __half2 b1p[256];
  int t = threadIdx.x;
  int ks = blockIdx.x & 7;
  int eb = blockIdx.x >> 3;
  int e0 = eb * 256;
  int w = t >> 6, l = t & 63;

  int kb = ks * 512;                       // real-k base of this slice
  {
    int j = t;
    if (j < 256) {
      #pragma unroll
      for (int d = 0; d < 4; ++d) {
        float2 v = *(const float2*)(w1 + d * 4096 + kb + 2 * j);
        w1p[d * 256 + j] = __floats2half2_rn(v.x, v.y);
      }
      float2 bv = *(const float2*)(b1 + kb + 2 * j);
      b1p[j] = __floats2half2_rn(bv.x, bv.y);
    }
  }

  // per-lane registers: x fragments (16 i-values per edge, 4 edges) + edge_attr (f16 pairs)
  int ibase = (l >> 4) * 8;
  __half2 xh[4][8];
  __half2 eah[4][4];
  #pragma unroll
  for (int m = 0; m < 4; ++m) {
    int e = e0 + w * 64 + m * 16 + (l & 15);
    if (e < N_EDGES) {
      int src = ei[e];
      const float* xp = x1 + src * 64;
      #pragma unroll
      for (int h = 0; h < 2; ++h) {
        float4 f0 = *(const float4*)(xp + ibase + h * 32);
        float4 f1 = *(const float4*)(xp + ibase + h * 32 + 4);
        xh[m][h * 4 + 0] = __floats2half2_rn(f0.x, f0.y);
        xh[m][h * 4 + 1] = __floats2half2_rn(f0.z, f0.w);
        xh[m][h * 4 + 2] = __floats2half2_rn(f1.x, f1.y);
        xh[m][h * 4 + 3] = __floats2half2_rn(f1.z, f1.w);
      }
      float4 av = *(const float4*)(ea + e * 4);
      eah[m][0] = __float2half2_rn(av.x); eah[m][1] = __float2half2_rn(av.y);
      eah[m][2] = __float2half2_rn(av.z); eah[m][3] = __float2half2_rn(av.w);
    } else {
      #pragma unroll
      for (int p = 0; p < 8; ++p) xh[m][p] = __floats2half2_rn(0.f, 0.f);
      #pragma unroll
      for (int d = 0; d < 4; ++d) eah[m][d] = __floats2half2_rn(0.f, 0.f);
    }
  }

  floatx4 zero4 = {0.f, 0.f, 0.f, 0.f};
  floatx4 acc[4][4];
  #pragma unroll
  for (int m = 0; m < 4; ++m)
    #pragma unroll
    for (int n = 0; n < 4; ++n) acc[m][n] = zero4;

  int nchunk = (ks == 7) ? 257 : 256;
  long long sbase = (long long)ks * 32768;

  // staging: thread t covers B' row r=t>>2, 16B-chunks cc = (t&3)+4j
  int r_row = t >> 2;
  int c4 = t & 3;
  const _Float16* browp = Bws + (size_t)r_row * BROW;

  auto stage_load = [&](int c, uint4* regs) {
    long long kk0 = sbase + (long long)c * 128;
    #pragma unroll
    for (int j = 0; j < 4; ++j) {
      int cc = c4 + j * 4;
      regs[j] = *(const uint4*)(browp + kk0 + cc * 8);
    }
  };
  auto stage_write = [&](int buf, uint4* regs) {
    #pragma unroll
    for (int j = 0; j < 4; ++j) {
      int cc = c4 + j * 4;
      int byteoff = r_row * 256 + ((cc ^ (r_row & 7)) << 4);   // XOR swizzle
      *(uint4*)((char*)&Bl[buf][0] + byteoff) = regs[j];
    }
  };

  uint4 st[4];
  stage_load(0, st);
  stage_write(0, st);
  __syncthreads();

  const __half  zero1 = __float2half(0.f);
  const __half2 one2  = __floats2half2_rn(1.f, 1.f);
  const __half2 zero2 = __floats2half2_rn(0.f, 0.f);

  int cur = 0;
  for (int c = 0; c < nchunk; ++c) {
    bool more = (c + 1 < nchunk);
    uint4 nx[4];
    if (more) stage_load(c + 1, nx);       // issue-early (T14); write-late below

    // z for this chunk's two real-k values (or bias rank); f16-pair math
    __half2 zh[4][2];
    if (c < 256) {
      __half2 w1v0 = w1p[c], w1v1 = w1p[256 + c], w1v2 = w1p[512 + c], w1v3 = w1p[768 + c];
      __half2 b1v = b1p[c];
      #pragma unroll
      for (int m = 0; m < 4; ++m) {
        __half2 h = __hfma2(eah[m][0], w1v0, b1v);
        h = __hfma2(eah[m][1], w1v1, h);
        h = __hfma2(eah[m][2], w1v2, h);
        h = __hfma2(eah[m][3], w1v3, h);
        __half zlo = __hmax(__low2half(h), zero1);    // ReLU (no __hmax2 in ROCm 7.2)
        __half zhi = __hmax(__high2half(h), zero1);
        zh[m][0] = __half2half2(zlo);
        zh[m][1] = __half2half2(zhi);
      }
    } else {  // bias chunk: k=4096 -> z=1 (picks up b2 term), k=4097 -> 0
      #pragma unroll
      for (int m = 0; m < 4; ++m) { zh[m][0] = one2; zh[m][1] = zero2; }
    }

    #pragma unroll
    for (int s = 0; s < 4; ++s) {
      half8_t bf[4];
      #pragma unroll
      for (int n = 0; n < 4; ++n) {
        int o = n * 16 + (l & 15);
        int cc = s * 4 + (l >> 4);
        int byteoff = o * 256 + ((cc ^ (o & 7)) << 4);
        bf[n] = *(const half8_t*)((const char*)&Bl[cur][0] + byteoff);
      }
      #pragma unroll
      for (int m = 0; m < 4; ++m) {
        __half2 zd = zh[m][s >> 1];
        union { half8_t v; __half2 p[4]; } af;
        #pragma unroll
        for (int p = 0; p < 4; ++p) af.p[p] = __hmul2(xh[m][(s & 1) * 4 + p], zd);
        #pragma unroll
        for (int n = 0; n < 4; ++n)
          acc[m][n] = __builtin_amdgcn_mfma_f32_16x16x32_f16(af.v, bf[n], acc[m][n], 0, 0, 0);
      }
    }

    if (more) stage_write(cur ^ 1, nx);
    __syncthreads();
    cur ^= 1;
  }

  // epilogue (C/D layout: col=lane&15, row=(lane>>4)*4+reg)
  if (PART) {
    float* pb = outbuf + ((size_t)ks * EPAD + e0 + w * 64) * 64 + (l & 15);
    #pragma unroll
    for (int m = 0; m < 4; ++m) {
      #pragma unroll
      for (int r = 0; r < 4; ++r) {
        int erow = m * 16 + (l >> 4) * 4 + r;
        float* rowp = pb + erow * 64;
        #pragma unroll
        for (int n = 0; n < 4; ++n) rowp[n * 16] = acc[m][n][r];
      }
    }
  } else {
    #pragma unroll
    for (int m = 0; m < 4; ++m) {
      #pragma unroll
      for (int r = 0; r < 4; ++r) {
        int e = e0 + w * 64 + m * 16 + (l >> 4) * 4 + r;
        if (e < N_EDGES) {
          int dst = ei[N_EDGES + e];
          float* ap = outbuf + dst * 64 + (l & 15);
          #pragma unroll
          for (int n = 0; n < 4; ++n) atomicAdd(ap + n * 16, acc[m][n][r]);
        }
      }
    }
  }
}

// ---------------- reduce 8 partial slices -> scatter into agg1 (8x fewer atomics)
__global__ void reduce_partials(const float* __restrict__ P8, const int* __restrict__ ei,
                                float* __restrict__ agg1) {
  int gid = blockIdx.x * 256 + threadIdx.x;
  if (gid >= N_EDGES * 64) return;
  int e = gid >> 6;
  float s = 0.f;
  #pragma unroll
  for (int ks = 0; ks < 8; ++ks) s += P8[(size_t)ks * PSLICE + gid];
  int dst = ei[N_EDGES + e];
  atomicAdd(&agg1[dst * 64 + (gid & 63)], s);
}

// ---------------- node update 1 + global mean pool accumulate
__global__ void node1_pool(const int* __restrict__ batch, const float* __restrict__ x1,
                           const float* __restrict__ agg1, const float* __restrict__ cnt,
                           const float* __restrict__ root1, const float* __restrict__ bias1,
                           float* __restrict__ psum) {
  __shared__ float rt[4096];
  int t = threadIdx.x;
  for (int idx = t; idx < 4096; idx += 256) rt[idx] = root1[idx];
  __syncthreads();
  int w = t >> 6, l = t & 63;
  int n = blockIdx.x * 4 + w;
  if (n >= N_NODES) return;
  float c = fmaxf(cnt[n], 1.f);
  float acc = agg1[n * 64 + l] / c + bias1[l];
  const float* xp = x1 + n * 64;
  #pragma unroll
  for (int i4 = 0; i4 < 16; ++i4) {
    float4 xv = *(const float4*)(xp + i4 * 4);
    acc += xv.x * rt[(i4 * 4 + 0) * 64 + l] + xv.y * rt[(i4 * 4 + 1) * 64 + l]
         + xv.z * rt[(i4 * 4 + 2) * 64 + l] + xv.w * rt[(i4 * 4 + 3) * 64 + l];
  }
  acc = fmaxf(acc, 0.f);
  atomicAdd(&psum[batch[n] * 64 + l], acc);
}

// ---------------- classifier head: one wave per graph
__global__ void classifier(const float* __restrict__ psum, const float* __restrict__ pcnt,
                           const float* __restrict__ wc1, const float* __restrict__ bc1,
                           const float* __restrict__ wc2, const float* __restrict__ bc2,
                           float* __restrict__ out) {
  __shared__ float hb[64];
  int g = blockIdx.x, j = threadIdx.x;
  float c = fmaxf(pcnt[g], 1.f);
  float h = bc1[j];
  const float* pp = psum + g * 64;
  #pragma unroll
  for (int i4 = 0; i4 < 16; ++i4) {
    float4 pv = *(const float4*)(pp + i4 * 4);
    h += (pv.x / c) * wc1[(i4 * 4 + 0) * 64 + j] + (pv.y / c) * wc1[(i4 * 4 + 1) * 64 + j]
       + (pv.z / c) * wc1[(i4 * 4 + 2) * 64 + j] + (pv.w / c) * wc1[(i4 * 4 + 3) * 64 + j];
  }
  hb[j] = fmaxf(h, 0.f);
  __syncthreads();
  if (j < 4) {
    float o = bc2[j];
    #pragma unroll
    for (int k = 0; k < 64; ++k) o += hb[k] * wc2[k * 4 + j];
    out[g * 4 + j] = o;
  }
}

extern "C" void kernel_launch(void* const* d_in, const int* in_sizes, int n_in,
                              void* d_out, int out_size, void* d_ws, size_t ws_size,
                              hipStream_t stream) {
  const float* node_ids = (const float*)d_in[0];
  const int*   ei       = (const int*)d_in[1];
  const float* ea       = (const float*)d_in[2];
  const int*   batch    = (const int*)d_in[3];
  const float* w1_0 = (const float*)d_in[4];
  const float* b1_0 = (const float*)d_in[5];
  const float* w2_0 = (const float*)d_in[6];
  const float* b2_0 = (const float*)d_in[7];
  const float* root0 = (const float*)d_in[8];
  const float* bias0 = (const float*)d_in[9];
  const float* w1_1 = (const float*)d_in[10];
  const float* b1_1 = (const float*)d_in[11];
  const float* w2_1 = (const float*)d_in[12];
  const float* b2_1 = (const float*)d_in[13];
  const float* root1 = (const float*)d_in[14];
  const float* bias1 = (const float*)d_in[15];
  const float* wc1 = (const float*)d_in[16];
  const float* bc1 = (const float*)d_in[17];
  const float* wc2 = (const float*)d_in[18];
  const float* bc2 = (const float*)d_in[19];
  float* out = (float*)d_out;

  char* ws = (char*)d_ws;
  _Float16* Bws = (_Float16*)ws;                       // 33,570,816 B
  float* x1   = (float*)(ws + 33570816);               //  2,560,000 B
  float* agg0 = (float*)(ws + 36130816);               //  2,560,000 B (zeroed)
  float* agg1 = (float*)(ws + 38690816);               //  2,560,000 B (zeroed)
  float* cnt  = (float*)(ws + 41250816);               //     40,000 B (zeroed)
  float* psum = (float*)(ws + 41290816);               //     16,384 B (zeroed)
  float* pcnt = (float*)(ws + 41307200);               //        256 B (zeroed)
  float* P8   = (float*)(ws + 41307456);               // 82,313,216 B (fully overwritten)
  const size_t NEED_PART = 41307456ull + (size_t)8 * PSLICE * 4;

  (void)hipMemsetAsync(agg0, 0, 2560000 + 2560000 + 40000 + 16384 + 256, stream);

  prep_B<<<(KKTOT + 255) / 256, 256, 0, stream>>>(w2_1, b2_1, Bws);
  layer0_edge<<<512, 256, 0, stream>>>(node_ids, ei, ea, w1_0, b1_0, w2_0, b2_0, agg0, cnt);
  node0<<<(N_NODES * 64 + 255) / 256, 256, 0, stream>>>(node_ids, batch, agg0, cnt, root0, bias0, x1, pcnt);

  if (ws_size >= NEED_PART) {
    fused_edge_gemm<true><<<157 * 8, 256, 0, stream>>>(ei, ea, x1, w1_1, b1_1, Bws, P8);
    reduce_partials<<<(N_EDGES * 64) / 256, 256, 0, stream>>>(P8, ei, agg1);
  } else {
    fused_edge_gemm<false><<<157 * 8, 256, 0, stream>>>(ei, ea, x1, w1_1, b1_1, Bws, agg1);
  }

  node1_pool<<<(N_NODES + 3) / 4, 256, 0, stream>>>(batch, x1, agg1, cnt, root1, bias1, psum);
  classifier<<<N_GRAPH, 64, 0, stream>>>(psum, pcnt, wc1, bc1, wc2, bc2, out);
}

// Round 5
// 1492.983 us; speedup vs baseline: 1.0832x; 1.0690x over previous
//
#include <hip/hip_runtime.h>
#include <hip/hip_fp16.h>

#define N_NODES 10000
#define N_EDGES 40000
#define N_GRAPH 64
#define KKREAL  262144          // 4096 * 64
#define KKTOT   262272          // + 128 (virtual k=4096 bias rank + zero pad)
#define BROW    KKTOT           // B' row stride in halves
#define EPAD    40192           // 157 * 256 padded edge count
#define PSLICE  (EPAD * 64)     // floats per partial slice

typedef _Float16 half8_t  __attribute__((ext_vector_type(8)));
typedef float    floatx16 __attribute__((ext_vector_type(16)));

__device__ __forceinline__ void gload_lds16(const void* g, void* l) {
  __builtin_amdgcn_global_load_lds((const __attribute__((address_space(1))) void*)g,
                                   (__attribute__((address_space(3))) void*)l, 16, 0, 0);
}

// swizzle: 16B-slot permutation within each row's 256B chunk image
__device__ __host__ __forceinline__ int swz(int row) {
  return ((row & 3) << 1) | ((row >> 2) & 1);
}

// ---------------- prep: B'[o][kk], PRE-SWIZZLED per 128-half chunk so a linear
// global_load_lds copy lands the bank-conflict-free LDS image.
// logical B'[o][kk_l] = w2_1[k][i*64+o] (kk_l = k*64+i), bias rank at k=4096.
__global__ void prep_B(const float* __restrict__ w2, const float* __restrict__ b2,
                       _Float16* __restrict__ Bws) {
  int kk = blockIdx.x * blockDim.x + threadIdx.x;
  if (kk >= KKTOT) return;
  int s = (kk >> 3) & 15, j3 = kk & 7;
  int basekk = kk & ~127;
  for (int o = 0; o < 64; ++o) {
    int kk_l = basekk | ((s ^ swz(o)) << 3) | j3;
    int k = kk_l >> 6, i = kk_l & 63;
    float v;
    if (k < 4096)       v = w2[k * 4096 + i * 64 + o];
    else if (k == 4096) v = b2[i * 64 + o];
    else                v = 0.f;
    Bws[(size_t)o * BROW + kk] = (_Float16)v;
  }
}

// ---------------- layer 0: per-edge MLP (in_dim=1) + scatter-sum + degree count
__global__ void layer0_edge(const float* __restrict__ node_ids,
                            const int* __restrict__ ei,
                            const float* __restrict__ ea,
                            const float* __restrict__ w1, const float* __restrict__ b1,
                            const float* __restrict__ w2, const float* __restrict__ b2,
                            float* __restrict__ agg0, float* __restrict__ cnt) {
  __shared__ float w1s[256], b1s[64], w2s[4096], b2s[64], zb[4][64];
  int t = threadIdx.x;
  for (int idx = t; idx < 4096; idx += 256) w2s[idx] = w2[idx];
  if (t < 256) w1s[t] = w1[t];
  if (t < 64) { b1s[t] = b1[t]; b2s[t] = b2[t]; }
  __syncthreads();
  int w = t >> 6, l = t & 63;
  int gw = blockIdx.x * 4 + w;
  int nw = gridDim.x * 4;
  for (int e = gw; e < N_EDGES; e += nw) {
    float a0 = ea[e * 4 + 0], a1 = ea[e * 4 + 1], a2 = ea[e * 4 + 2], a3 = ea[e * 4 + 3];
    float z = a0 * w1s[l] + a1 * w1s[64 + l] + a2 * w1s[128 + l] + a3 * w1s[192 + l] + b1s[l];
    zb[w][l] = fmaxf(z, 0.f);
    asm volatile("s_waitcnt lgkmcnt(0)" ::: "memory");
    __builtin_amdgcn_sched_barrier(0);
    float h = b2s[l];
    #pragma unroll
    for (int k = 0; k < 64; ++k) h += zb[w][k] * w2s[k * 64 + l];
    int src = ei[e], dst = ei[N_EDGES + e];
    float msg = node_ids[src] * h;
    atomicAdd(&agg0[dst * 64 + l], msg);
    if (l == 0) atomicAdd(&cnt[dst], 1.0f);
  }
}

// ---------------- node update 0: x1 = relu(agg0/cnt + node_ids*root0 + bias0); pool counts
__global__ void node0(const float* __restrict__ node_ids, const int* __restrict__ batch,
                      const float* __restrict__ agg0, const float* __restrict__ cnt,
                      const float* __restrict__ root0, const float* __restrict__ bias0,
                      float* __restrict__ x1, float* __restrict__ pcnt) {
  int gid = blockIdx.x * 256 + threadIdx.x;
  if (gid >= N_NODES * 64) return;
  int n = gid >> 6, o = gid & 63;
  float c = fmaxf(cnt[n], 1.f);
  float v = agg0[gid] / c + node_ids[n] * root0[o] + bias0[o];
  x1[gid] = fmaxf(v, 0.f);
  if (o == 0) atomicAdd(&pcnt[batch[n]], 1.0f);
}

// ---------------- layer 1 fused: msg[e,o] = sum_kk (z_e[k]*x_e[i]) * B'[kk,o]
// grid = 157 edge-blocks * 8 K-slices; block = 256 thr = 4 waves (2 edge-grp x 2 o-grp)
// Wave: 128 edges (4 tiles of 32) x 32 o; 32x32x16 f16 MFMA; B' via global_load_lds.
template <bool PART>
__launch_bounds__(256, 3)
__global__ void fused_edge_gemm(const int* __restrict__ ei,
                                const float* __restrict__ ea,
                                const float* __restrict__ x1,
                                const float* __restrict__ w1, const float* __restrict__ b1,
                                const _Float16* __restrict__ Bws,
                                float* __restrict__ outbuf) {
  __shared__ __attribute__((aligned(16))) _Float16 Bl[2][64 * 128]; // swizzled image
  __shared__ __half2 w1p[4 * 256];   // (w1[d][kb+2c], w1[d][kb+2c+1])
  __shared__ __half2 b1p[256];
  int t = threadIdx.x;
  int ks = blockIdx.x & 7;           // K-slice; blockIdx%8 == XCD -> slice-per-XCD L2 affinity
  int eb = blockIdx.x >> 3;
  int e0 = eb * 256;
  int w = t >> 6, l = t & 63;
  int half_ = l >> 5;                // which 8-of-16 joint-k slice
  int lane31 = l & 31;
  int wr = w >> 1;                   // edge group (128 edges)
  int wc = w & 1;                    // o group (32 outs)
  int orow = wc * 32 + lane31;
  int swo = swz(orow);

  int kb = ks * 512;                 // real-k base of this slice
  {
    int j = t;
    #pragma unroll
    for (int d = 0; d < 4; ++d) {
      float2 v = *(const float2*)(w1 + d * 4096 + kb + 2 * j);
      w1p[d * 256 + j] = __floats2half2_rn(v.x, v.y);
    }
    float2 bv = *(const float2*)(b1 + kb + 2 * j);
    b1p[j] = __floats2half2_rn(bv.x, bv.y);
  }

  // per-lane A data: 4 edge-tiles; lane holds x[row=lane31][q*16 + half_*8 + 0..7], q=0..3
  __half2 xh[4][4][4];
  __half2 eab[4][2];                 // packed edge attrs (a0,a1),(a2,a3)
  #pragma unroll
  for (int m = 0; m < 4; ++m) {
    int e = e0 + wr * 128 + m * 32 + lane31;
    if (e < N_EDGES) {
      int src = ei[e];
      const float* xp = x1 + src * 64 + half_ * 8;
      #pragma unroll
      for (int q = 0; q < 4; ++q) {
        float4 f0 = *(const float4*)(xp + q * 16);
        float4 f1 = *(const float4*)(xp + q * 16 + 4);
        xh[m][q][0] = __floats2half2_rn(f0.x, f0.y);
        xh[m][q][1] = __floats2half2_rn(f0.z, f0.w);
        xh[m][q][2] = __floats2half2_rn(f1.x, f1.y);
        xh[m][q][3] = __floats2half2_rn(f1.z, f1.w);
      }
      float4 av = *(const float4*)(ea + e * 4);
      eab[m][0] = __floats2half2_rn(av.x, av.y);
      eab[m][1] = __floats2half2_rn(av.z, av.w);
    } else {
      #pragma unroll
      for (int q = 0; q < 4; ++q)
        #pragma unroll
        for (int p = 0; p < 4; ++p) xh[m][q][p] = __floats2half2_rn(0.f, 0.f);
      eab[m][0] = eab[m][1] = __floats2half2_rn(0.f, 0.f);
    }
  }

  floatx16 acc[4];
  #pragma unroll
  for (int m = 0; m < 4; ++m)
    #pragma unroll
    for (int r = 0; r < 16; ++r) acc[m][r] = 0.f;

  int nchunk = (ks == 7) ? 257 : 256;
  size_t sbase_b = (size_t)ks * 65536;          // slice base, bytes (32768 halves)
  const char* Bb = (const char*)Bws;

  // stage chunk c into Bl[buf] via linear DMA (image is pre-swizzled in global).
  // LDS dest is HW base+lane*16; global src is fully per-lane: row (l>>4) AND
  // 16B column (l&15) inside the 256B chunk row.
  int colb = (l & 15) * 16;
  auto stage = [&](int buf, int c) {
    const char* srcb = Bb + sbase_b + (size_t)c * 256 + colb;
    char* dstb = (char*)&Bl[buf][0] + w * 4096 + l * 16;
    #pragma unroll
    for (int j = 0; j < 4; ++j) {
      int row = w * 16 + j * 4 + (l >> 4);
      gload_lds16(srcb + (size_t)row * (BROW * 2), dstb + j * 1024);
    }
  };

  stage(0, 0);
  __syncthreads();

  const __half  zero1 = __float2half(0.f);
  const __half2 one2  = __floats2half2_rn(1.f, 1.f);
  const __half2 zero2 = __floats2half2_rn(0.f, 0.f);

  int cur = 0;
  for (int c = 0; c < nchunk; ++c) {
    if (c + 1 < nchunk) stage(cur ^ 1, c + 1);   // DMA lands during compute

    // z for the chunk's two real k values (broadcast h2 per edge-tile)
    __half2 zbc[4][2];
    if (c < 256) {
      __half2 w1v0 = w1p[c], w1v1 = w1p[256 + c], w1v2 = w1p[512 + c], w1v3 = w1p[768 + c];
      __half2 b1v = b1p[c];
      #pragma unroll
      for (int m = 0; m < 4; ++m) {
        __half2 a01 = eab[m][0], a23 = eab[m][1];
        __half2 h = __hfma2(__half2half2(__low2half(a01)),  w1v0, b1v);
        h = __hfma2(__half2half2(__high2half(a01)), w1v1, h);
        h = __hfma2(__half2half2(__low2half(a23)),  w1v2, h);
        h = __hfma2(__half2half2(__high2half(a23)), w1v3, h);
        zbc[m][0] = __half2half2(__hmax(__low2half(h),  zero1));
        zbc[m][1] = __half2half2(__hmax(__high2half(h), zero1));
      }
    } else {  // bias chunk: k=4096 -> z=1 (picks up b2), k=4097 -> 0
      #pragma unroll
      for (int m = 0; m < 4; ++m) { zbc[m][0] = one2; zbc[m][1] = zero2; }
    }

    const char* blc = (const char*)&Bl[cur][0] + orow * 256;
    #pragma unroll
    for (int t8 = 0; t8 < 8; ++t8) {            // kstep of 16 joint-kk
      int slot = (t8 * 2 + half_) ^ swo;
      half8_t bf = *(const half8_t*)(blc + slot * 16);
      #pragma unroll
      for (int m = 0; m < 4; ++m) {
        union { half8_t v; __half2 p[4]; } af;
        #pragma unroll
        for (int p = 0; p < 4; ++p) af.p[p] = __hmul2(xh[m][t8 & 3][p], zbc[m][t8 >> 2]);
        acc[m] = __builtin_amdgcn_mfma_f32_32x32x16_f16(af.v, bf, acc[m], 0, 0, 0);
      }
    }

    __syncthreads();   // waits own DMA (vmcnt) + all waves done reading Bl[cur]
    cur ^= 1;
  }

  // epilogue: 32x32 C/D layout: col=lane&31, row=(reg&3)+8*(reg>>2)+4*(lane>>5)
  if (PART) {
    float* pb = outbuf + ((size_t)ks * EPAD + e0 + wr * 128) * 64 + wc * 32 + lane31;
    #pragma unroll
    for (int m = 0; m < 4; ++m) {
      #pragma unroll
      for (int r = 0; r < 16; ++r) {
        int row = m * 32 + (r & 3) + 8 * (r >> 2) + 4 * half_;
        pb[(size_t)row * 64] = acc[m][r];
      }
    }
  } else {
    #pragma unroll
    for (int m = 0; m < 4; ++m) {
      #pragma unroll
      for (int r = 0; r < 16; ++r) {
        int e = e0 + wr * 128 + m * 32 + (r & 3) + 8 * (r >> 2) + 4 * half_;
        if (e < N_EDGES) {
          int dst = ei[N_EDGES + e];
          atomicAdd(&outbuf[dst * 64 + wc * 32 + lane31], acc[m][r]);
        }
      }
    }
  }
}

// ---------------- reduce 8 partial slices -> scatter into agg1 (8x fewer atomics)
__global__ void reduce_partials(const float* __restrict__ P8, const int* __restrict__ ei,
                                float* __restrict__ agg1) {
  int gid = blockIdx.x * 256 + threadIdx.x;
  if (gid >= N_EDGES * 64) return;
  int e = gid >> 6;
  float s = 0.f;
  #pragma unroll
  for (int ks = 0; ks < 8; ++ks) s += P8[(size_t)ks * PSLICE + gid];
  int dst = ei[N_EDGES + e];
  atomicAdd(&agg1[dst * 64 + (gid & 63)], s);
}

// ---------------- node update 1 + global mean pool accumulate
__global__ void node1_pool(const int* __restrict__ batch, const float* __restrict__ x1,
                           const float* __restrict__ agg1, const float* __restrict__ cnt,
                           const float* __restrict__ root1, const float* __restrict__ bias1,
                           float* __restrict__ psum) {
  __shared__ float rt[4096];
  int t = threadIdx.x;
  for (int idx = t; idx < 4096; idx += 256) rt[idx] = root1[idx];
  __syncthreads();
  int w = t >> 6, l = t & 63;
  int n = blockIdx.x * 4 + w;
  if (n >= N_NODES) return;
  float c = fmaxf(cnt[n], 1.f);
  float acc = agg1[n * 64 + l] / c + bias1[l];
  const float* xp = x1 + n * 64;
  #pragma unroll
  for (int i4 = 0; i4 < 16; ++i4) {
    float4 xv = *(const float4*)(xp + i4 * 4);
    acc += xv.x * rt[(i4 * 4 + 0) * 64 + l] + xv.y * rt[(i4 * 4 + 1) * 64 + l]
         + xv.z * rt[(i4 * 4 + 2) * 64 + l] + xv.w * rt[(i4 * 4 + 3) * 64 + l];
  }
  acc = fmaxf(acc, 0.f);
  atomicAdd(&psum[batch[n] * 64 + l], acc);
}

// ---------------- classifier head: one wave per graph
__global__ void classifier(const float* __restrict__ psum, const float* __restrict__ pcnt,
                           const float* __restrict__ wc1, const float* __restrict__ bc1,
                           const float* __restrict__ wc2, const float* __restrict__ bc2,
                           float* __restrict__ out) {
  __shared__ float hb[64];
  int g = blockIdx.x, j = threadIdx.x;
  float c = fmaxf(pcnt[g], 1.f);
  float h = bc1[j];
  const float* pp = psum + g * 64;
  #pragma unroll
  for (int i4 = 0; i4 < 16; ++i4) {
    float4 pv = *(const float4*)(pp + i4 * 4);
    h += (pv.x / c) * wc1[(i4 * 4 + 0) * 64 + j] + (pv.y / c) * wc1[(i4 * 4 + 1) * 64 + j]
       + (pv.z / c) * wc1[(i4 * 4 + 2) * 64 + j] + (pv.w / c) * wc1[(i4 * 4 + 3) * 64 + j];
  }
  hb[j] = fmaxf(h, 0.f);
  __syncthreads();
  if (j < 4) {
    float o = bc2[j];
    #pragma unroll
    for (int k = 0; k < 64; ++k) o += hb[k] * wc2[k * 4 + j];
    out[g * 4 + j] = o;
  }
}

extern "C" void kernel_launch(void* const* d_in, const int* in_sizes, int n_in,
                              void* d_out, int out_size, void* d_ws, size_t ws_size,
                              hipStream_t stream) {
  const float* node_ids = (const float*)d_in[0];
  const int*   ei       = (const int*)d_in[1];
  const float* ea       = (const float*)d_in[2];
  const int*   batch    = (const int*)d_in[3];
  const float* w1_0 = (const float*)d_in[4];
  const float* b1_0 = (const float*)d_in[5];
  const float* w2_0 = (const float*)d_in[6];
  const float* b2_0 = (const float*)d_in[7];
  const float* root0 = (const float*)d_in[8];
  const float* bias0 = (const float*)d_in[9];
  const float* w1_1 = (const float*)d_in[10];
  const float* b1_1 = (const float*)d_in[11];
  const float* w2_1 = (const float*)d_in[12];
  const float* b2_1 = (const float*)d_in[13];
  const float* root1 = (const float*)d_in[14];
  const float* bias1 = (const float*)d_in[15];
  const float* wc1 = (const float*)d_in[16];
  const float* bc1 = (const float*)d_in[17];
  const float* wc2 = (const float*)d_in[18];
  const float* bc2 = (const float*)d_in[19];
  float* out = (float*)d_out;

  char* ws = (char*)d_ws;
  _Float16* Bws = (_Float16*)ws;                       // 33,570,816 B
  float* x1   = (float*)(ws + 33570816);               //  2,560,000 B
  float* agg0 = (float*)(ws + 36130816);               //  2,560,000 B (zeroed)
  float* agg1 = (float*)(ws + 38690816);               //  2,560,000 B (zeroed)
  float* cnt  = (float*)(ws + 41250816);               //     40,000 B (zeroed)
  float* psum = (float*)(ws + 41290816);               //     16,384 B (zeroed)
  float* pcnt = (float*)(ws + 41307200);               //        256 B (zeroed)
  float* P8   = (float*)(ws + 41307456);               // 82,313,216 B (fully overwritten)
  const size_t NEED_PART = 41307456ull + (size_t)8 * PSLICE * 4;

  (void)hipMemsetAsync(agg0, 0, 2560000 + 2560000 + 40000 + 16384 + 256, stream);

  prep_B<<<(KKTOT + 255) / 256, 256, 0, stream>>>(w2_1, b2_1, Bws);
  layer0_edge<<<512, 256, 0, stream>>>(node_ids, ei, ea, w1_0, b1_0, w2_0, b2_0, agg0, cnt);
  node0<<<(N_NODES * 64 + 255) / 256, 256, 0, stream>>>(node_ids, batch, agg0, cnt, root0, bias0, x1, pcnt);

  if (ws_size >= NEED_PART) {
    fused_edge_gemm<true><<<157 * 8, 256, 0, stream>>>(ei, ea, x1, w1_1, b1_1, Bws, P8);
    reduce_partials<<<(N_EDGES * 64) / 256, 256, 0, stream>>>(P8, ei, agg1);
  } else {
    fused_edge_gemm<false><<<157 * 8, 256, 0, stream>>>(ei, ea, x1, w1_1, b1_1, Bws, agg1);
  }

  node1_pool<<<(N_NODES + 3) / 4, 256, 0, stream>>>(batch, x1, agg1, cnt, root1, bias1, psum);
  classifier<<<N_GRAPH, 64, 0, stream>>>(psum, pcnt, wc1, bc1, wc2, bc2, out);
}

// Round 6
// 1235.702 us; speedup vs baseline: 1.3087x; 1.2082x over previous
//
#include <hip/hip_runtime.h>
#include <hip/hip_fp16.h>

#define N_NODES 10000
#define N_EDGES 40000
#define N_GRAPH 64
#define KKREAL  262144          // 4096 * 64
#define KKTOT   262272          // + 128 (virtual k=4096 bias rank + zero pad)
#define BROW    KKTOT           // B' row stride in halves
#define EPAD    40192           // 157 * 256 padded edge count
#define PSLICE  (EPAD * 64)     // floats per partial slice

typedef _Float16 half8_t  __attribute__((ext_vector_type(8)));
typedef float    floatx16 __attribute__((ext_vector_type(16)));

__device__ __forceinline__ void gload_lds16(const void* g, void* l) {
  __builtin_amdgcn_global_load_lds((const __attribute__((address_space(1))) void*)g,
                                   (__attribute__((address_space(3))) void*)l, 16, 0, 0);
}

// swizzle: 16B-slot permutation within each row's 256B chunk image (bits 0-2 of row only)
__device__ __host__ __forceinline__ int swz(int row) {
  return ((row & 3) << 1) | ((row >> 2) & 1);
}

__device__ __forceinline__ half8_t splat8(_Float16 v) {
  half8_t r = {v, v, v, v, v, v, v, v};
  return r;
}

// ---------------- prep: B'[o][kk], PRE-SWIZZLED per 128-half chunk so a linear
// global_load_lds copy lands the bank-conflict-free LDS image.
// logical B'[o][kk_l] = w2_1[k][i*64+o] (kk_l = k*64+i), bias rank at k=4096.
__global__ void prep_B(const float* __restrict__ w2, const float* __restrict__ b2,
                       _Float16* __restrict__ Bws) {
  int kk = blockIdx.x * blockDim.x + threadIdx.x;
  if (kk >= KKTOT) return;
  int s = (kk >> 3) & 15, j3 = kk & 7;
  int basekk = kk & ~127;
  for (int o = 0; o < 64; ++o) {
    int kk_l = basekk | ((s ^ swz(o)) << 3) | j3;
    int k = kk_l >> 6, i = kk_l & 63;
    float v;
    if (k < 4096)       v = w2[k * 4096 + i * 64 + o];
    else if (k == 4096) v = b2[i * 64 + o];
    else                v = 0.f;
    Bws[(size_t)o * BROW + kk] = (_Float16)v;
  }
}

// ---------------- layer 0: per-edge MLP (in_dim=1) + scatter-sum + degree count
__global__ void layer0_edge(const float* __restrict__ node_ids,
                            const int* __restrict__ ei,
                            const float* __restrict__ ea,
                            const float* __restrict__ w1, const float* __restrict__ b1,
                            const float* __restrict__ w2, const float* __restrict__ b2,
                            float* __restrict__ agg0, float* __restrict__ cnt) {
  __shared__ float w1s[256], b1s[64], w2s[4096], b2s[64], zb[4][64];
  int t = threadIdx.x;
  for (int idx = t; idx < 4096; idx += 256) w2s[idx] = w2[idx];
  if (t < 256) w1s[t] = w1[t];
  if (t < 64) { b1s[t] = b1[t]; b2s[t] = b2[t]; }
  __syncthreads();
  int w = t >> 6, l = t & 63;
  int gw = blockIdx.x * 4 + w;
  int nw = gridDim.x * 4;
  for (int e = gw; e < N_EDGES; e += nw) {
    float a0 = ea[e * 4 + 0], a1 = ea[e * 4 + 1], a2 = ea[e * 4 + 2], a3 = ea[e * 4 + 3];
    float z = a0 * w1s[l] + a1 * w1s[64 + l] + a2 * w1s[128 + l] + a3 * w1s[192 + l] + b1s[l];
    zb[w][l] = fmaxf(z, 0.f);
    asm volatile("s_waitcnt lgkmcnt(0)" ::: "memory");
    __builtin_amdgcn_sched_barrier(0);
    float h = b2s[l];
    #pragma unroll
    for (int k = 0; k < 64; ++k) h += zb[w][k] * w2s[k * 64 + l];
    int src = ei[e], dst = ei[N_EDGES + e];
    float msg = node_ids[src] * h;
    atomicAdd(&agg0[dst * 64 + l], msg);
    if (l == 0) atomicAdd(&cnt[dst], 1.0f);
  }
}

// ---------------- node update 0: x1 = relu(agg0/cnt + node_ids*root0 + bias0); pool counts
__global__ void node0(const float* __restrict__ node_ids, const int* __restrict__ batch,
                      const float* __restrict__ agg0, const float* __restrict__ cnt,
                      const float* __restrict__ root0, const float* __restrict__ bias0,
                      float* __restrict__ x1, float* __restrict__ pcnt) {
  int gid = blockIdx.x * 256 + threadIdx.x;
  if (gid >= N_NODES * 64) return;
  int n = gid >> 6, o = gid & 63;
  float c = fmaxf(cnt[n], 1.f);
  float v = agg0[gid] / c + node_ids[n] * root0[o] + bias0[o];
  x1[gid] = fmaxf(v, 0.f);
  if (o == 0) atomicAdd(&pcnt[batch[n]], 1.0f);
}

// ---------------- layer 1 fused: msg[e,o] = sum_kk (z_e[k]*x_e[i]) * B'[kk,o]
// grid = 157 edge-blocks * 8 K-slices; block = 256 thr = 4 waves.
// Wave: 64 edges (2 tiles of 32) x ALL 64 o (n=2): each A-build feeds 2 MFMAs.
template <bool PART>
__launch_bounds__(256, 3)
__global__ void fused_edge_gemm(const int* __restrict__ ei,
                                const float* __restrict__ ea,
                                const float* __restrict__ x1,
                                const float* __restrict__ w1, const float* __restrict__ b1,
                                const _Float16* __restrict__ Bws,
                                float* __restrict__ outbuf) {
  __shared__ __attribute__((aligned(16))) _Float16 Bl[2][64 * 128]; // swizzled image
  __shared__ __attribute__((aligned(16))) __half2 w1q[256][4];      // 4 w1 pairs per c
  __shared__ __half2 b1p[256];
  int t = threadIdx.x;
  int ks = blockIdx.x & 7;           // K-slice
  int eb = blockIdx.x >> 3;
  int e0 = eb * 256;
  int w = t >> 6, l = t & 63;
  int half_ = l >> 5;                // A/B fragment k-half
  int lane31 = l & 31;
  int swo = swz(lane31);             // same for lane31 and lane31+32 (bits 0-2 only)

  int kb = ks * 512;                 // real-k base of this slice
  {
    int j = t;
    #pragma unroll
    for (int d = 0; d < 4; ++d) {
      float2 v = *(const float2*)(w1 + d * 4096 + kb + 2 * j);
      w1q[j][d] = __floats2half2_rn(v.x, v.y);
    }
    float2 bv = *(const float2*)(b1 + kb + 2 * j);
    b1p[j] = __floats2half2_rn(bv.x, bv.y);
  }

  // per-lane A data: 2 edge-tiles of 32; lane holds x[row=lane31][q*16 + half_*8 + 0..7]
  half8_t xh8[2][4];
  __half2 eb_bc[2][4];               // broadcast edge attrs
  #pragma unroll
  for (int m = 0; m < 2; ++m) {
    int e = e0 + w * 64 + m * 32 + lane31;
    if (e < N_EDGES) {
      int src = ei[e];
      const float* xp = x1 + src * 64 + half_ * 8;
      #pragma unroll
      for (int q = 0; q < 4; ++q) {
        float4 f0 = *(const float4*)(xp + q * 16);
        float4 f1 = *(const float4*)(xp + q * 16 + 4);
        half8_t v;
        v[0] = (_Float16)f0.x; v[1] = (_Float16)f0.y;
        v[2] = (_Float16)f0.z; v[3] = (_Float16)f0.w;
        v[4] = (_Float16)f1.x; v[5] = (_Float16)f1.y;
        v[6] = (_Float16)f1.z; v[7] = (_Float16)f1.w;
        xh8[m][q] = v;
      }
      float4 av = *(const float4*)(ea + e * 4);
      eb_bc[m][0] = __float2half2_rn(av.x); eb_bc[m][1] = __float2half2_rn(av.y);
      eb_bc[m][2] = __float2half2_rn(av.z); eb_bc[m][3] = __float2half2_rn(av.w);
    } else {
      #pragma unroll
      for (int q = 0; q < 4; ++q) xh8[m][q] = splat8((_Float16)0.f);
      #pragma unroll
      for (int d = 0; d < 4; ++d) eb_bc[m][d] = __float2half2_rn(0.f);
    }
  }

  floatx16 acc[2][2];
  #pragma unroll
  for (int m = 0; m < 2; ++m)
    #pragma unroll
    for (int n = 0; n < 2; ++n)
      #pragma unroll
      for (int r = 0; r < 16; ++r) acc[m][n][r] = 0.f;

  int nchunk = (ks == 7) ? 257 : 256;
  size_t sbase_b = (size_t)ks * 65536;          // slice base, bytes
  const char* Bb = (const char*)Bws;

  // stage: per-lane global src (pre-swizzled image) -> linear LDS DMA.
  // pointers advance by 256 B per chunk instead of full recompute.
  const char* srcp[4];
  {
    int colb = (l & 15) * 16;
    #pragma unroll
    for (int j = 0; j < 4; ++j) {
      int row = w * 16 + j * 4 + (l >> 4);
      srcp[j] = Bb + sbase_b + (size_t)row * (BROW * 2) + colb;
    }
  }
  char* dst0 = (char*)&Bl[0][0] + w * 4096 + l * 16;
  char* dst1 = (char*)&Bl[1][0] + w * 4096 + l * 16;

  auto stage = [&](int buf) {   // stages the chunk at current srcp, then advances
    char* dstb = buf ? dst1 : dst0;
    #pragma unroll
    for (int j = 0; j < 4; ++j) {
      gload_lds16(srcp[j], dstb + j * 1024);
      srcp[j] += 256;
    }
  };

  stage(0);
  __syncthreads();

  const __half zero1 = __float2half(0.f);
  union H2F { __half2 h2; _Float16 f[2]; };

  int cur = 0;
  for (int c = 0; c < nchunk; ++c) {
    if (c + 1 < nchunk) stage(cur ^ 1);   // DMA lands during compute

    // z for the chunk's two real k values -> splatted half8 multipliers
    half8_t zs8[2][2];
    if (c < 256) {
      __half2 w0 = w1q[c][0], w1v = w1q[c][1], w2v = w1q[c][2], w3v = w1q[c][3];
      __half2 bv = b1p[c];
      #pragma unroll
      for (int m = 0; m < 2; ++m) {
        __half2 h = __hfma2(eb_bc[m][0], w0, bv);
        h = __hfma2(eb_bc[m][1], w1v, h);
        h = __hfma2(eb_bc[m][2], w2v, h);
        h = __hfma2(eb_bc[m][3], w3v, h);
        H2F u; u.h2 = __halves2half2(__hmax(__low2half(h),  zero1),
                                     __hmax(__high2half(h), zero1));
        zs8[m][0] = splat8(u.f[0]);
        zs8[m][1] = splat8(u.f[1]);
      }
    } else {  // bias chunk: k=4096 -> z=1 (picks up b2), k=4097 -> 0
      #pragma unroll
      for (int m = 0; m < 2; ++m) {
        zs8[m][0] = splat8((_Float16)1.f);
        zs8[m][1] = splat8((_Float16)0.f);
      }
    }

    const char* blc = (const char*)&Bl[cur][0] + lane31 * 256;
    #pragma unroll
    for (int t8 = 0; t8 < 8; ++t8) {            // kstep of 16 joint-kk
      int slot = (t8 * 2 + half_) ^ swo;
      const char* ba = blc + slot * 16;
      half8_t bf0 = *(const half8_t*)ba;             // o rows 0..31
      half8_t bf1 = *(const half8_t*)(ba + 8192);    // o rows 32..63 (same swizzle)
      #pragma unroll
      for (int m = 0; m < 2; ++m) {
        half8_t af = xh8[m][t8 & 3] * zs8[m][t8 >> 2];   // 4 v_pk_mul, no movs
        acc[m][0] = __builtin_amdgcn_mfma_f32_32x32x16_f16(af, bf0, acc[m][0], 0, 0, 0);
        acc[m][1] = __builtin_amdgcn_mfma_f32_32x32x16_f16(af, bf1, acc[m][1], 0, 0, 0);
      }
    }

    __syncthreads();   // all waves' DMAs drained (vmcnt) + reads of Bl[cur] done
    cur ^= 1;
  }

  // epilogue: 32x32 C/D layout: col=lane&31, row=(reg&3)+8*(reg>>2)+4*(lane>>5)
  if (PART) {
    float* pb = outbuf + ((size_t)ks * EPAD + e0 + w * 64) * 64 + lane31;
    #pragma unroll
    for (int m = 0; m < 2; ++m) {
      #pragma unroll
      for (int r = 0; r < 16; ++r) {
        int row = m * 32 + (r & 3) + 8 * (r >> 2) + 4 * half_;
        pb[(size_t)row * 64]      = acc[m][0][r];
        pb[(size_t)row * 64 + 32] = acc[m][1][r];
      }
    }
  } else {
    #pragma unroll
    for (int m = 0; m < 2; ++m) {
      #pragma unroll
      for (int r = 0; r < 16; ++r) {
        int e = e0 + w * 64 + m * 32 + (r & 3) + 8 * (r >> 2) + 4 * half_;
        if (e < N_EDGES) {
          int dst = ei[N_EDGES + e];
          atomicAdd(&outbuf[dst * 64 + lane31],      acc[m][0][r]);
          atomicAdd(&outbuf[dst * 64 + lane31 + 32], acc[m][1][r]);
        }
      }
    }
  }
}

// ---------------- reduce 8 partial slices -> scatter into agg1 (8x fewer atomics)
__global__ void reduce_partials(const float* __restrict__ P8, const int* __restrict__ ei,
                                float* __restrict__ agg1) {
  int gid = blockIdx.x * 256 + threadIdx.x;
  if (gid >= N_EDGES * 64) return;
  int e = gid >> 6;
  float s = 0.f;
  #pragma unroll
  for (int ks = 0; ks < 8; ++ks) s += P8[(size_t)ks * PSLICE + gid];
  int dst = ei[N_EDGES + e];
  atomicAdd(&agg1[dst * 64 + (gid & 63)], s);
}

// ---------------- node update 1 + global mean pool accumulate
__global__ void node1_pool(const int* __restrict__ batch, const float* __restrict__ x1,
                           const float* __restrict__ agg1, const float* __restrict__ cnt,
                           const float* __restrict__ root1, const float* __restrict__ bias1,
                           float* __restrict__ psum) {
  __shared__ float rt[4096];
  int t = threadIdx.x;
  for (int idx = t; idx < 4096; idx += 256) rt[idx] = root1[idx];
  __syncthreads();
  int w = t >> 6, l = t & 63;
  int n = blockIdx.x * 4 + w;
  if (n >= N_NODES) return;
  float c = fmaxf(cnt[n], 1.f);
  float acc = agg1[n * 64 + l] / c + bias1[l];
  const float* xp = x1 + n * 64;
  #pragma unroll
  for (int i4 = 0; i4 < 16; ++i4) {
    float4 xv = *(const float4*)(xp + i4 * 4);
    acc += xv.x * rt[(i4 * 4 + 0) * 64 + l] + xv.y * rt[(i4 * 4 + 1) * 64 + l]
         + xv.z * rt[(i4 * 4 + 2) * 64 + l] + xv.w * rt[(i4 * 4 + 3) * 64 + l];
  }
  acc = fmaxf(acc, 0.f);
  atomicAdd(&psum[batch[n] * 64 + l], acc);
}

// ---------------- classifier head: one wave per graph
__global__ void classifier(const float* __restrict__ psum, const float* __restrict__ pcnt,
                           const float* __restrict__ wc1, const float* __restrict__ bc1,
                           const float* __restrict__ wc2, const float* __restrict__ bc2,
                           float* __restrict__ out) {
  __shared__ float hb[64];
  int g = blockIdx.x, j = threadIdx.x;
  float c = fmaxf(pcnt[g], 1.f);
  float h = bc1[j];
  const float* pp = psum + g * 64;
  #pragma unroll
  for (int i4 = 0; i4 < 16; ++i4) {
    float4 pv = *(const float4*)(pp + i4 * 4);
    h += (pv.x / c) * wc1[(i4 * 4 + 0) * 64 + j] + (pv.y / c) * wc1[(i4 * 4 + 1) * 64 + j]
       + (pv.z / c) * wc1[(i4 * 4 + 2) * 64 + j] + (pv.w / c) * wc1[(i4 * 4 + 3) * 64 + j];
  }
  hb[j] = fmaxf(h, 0.f);
  __syncthreads();
  if (j < 4) {
    float o = bc2[j];
    #pragma unroll
    for (int k = 0; k < 64; ++k) o += hb[k] * wc2[k * 4 + j];
    out[g * 4 + j] = o;
  }
}

extern "C" void kernel_launch(void* const* d_in, const int* in_sizes, int n_in,
                              void* d_out, int out_size, void* d_ws, size_t ws_size,
                              hipStream_t stream) {
  const float* node_ids = (const float*)d_in[0];
  const int*   ei       = (const int*)d_in[1];
  const float* ea       = (const float*)d_in[2];
  const int*   batch    = (const int*)d_in[3];
  const float* w1_0 = (const float*)d_in[4];
  const float* b1_0 = (const float*)d_in[5];
  const float* w2_0 = (const float*)d_in[6];
  const float* b2_0 = (const float*)d_in[7];
  const float* root0 = (const float*)d_in[8];
  const float* bias0 = (const float*)d_in[9];
  const float* w1_1 = (const float*)d_in[10];
  const float* b1_1 = (const float*)d_in[11];
  const float* w2_1 = (const float*)d_in[12];
  const float* b2_1 = (const float*)d_in[13];
  const float* root1 = (const float*)d_in[14];
  const float* bias1 = (const float*)d_in[15];
  const float* wc1 = (const float*)d_in[16];
  const float* bc1 = (const float*)d_in[17];
  const float* wc2 = (const float*)d_in[18];
  const float* bc2 = (const float*)d_in[19];
  float* out = (float*)d_out;

  char* ws = (char*)d_ws;
  _Float16* Bws = (_Float16*)ws;                       // 33,570,816 B
  float* x1   = (float*)(ws + 33570816);               //  2,560,000 B
  float* agg0 = (float*)(ws + 36130816);               //  2,560,000 B (zeroed)
  float* agg1 = (float*)(ws + 38690816);               //  2,560,000 B (zeroed)
  float* cnt  = (float*)(ws + 41250816);               //     40,000 B (zeroed)
  float* psum = (float*)(ws + 41290816);               //     16,384 B (zeroed)
  float* pcnt = (float*)(ws + 41307200);               //        256 B (zeroed)
  float* P8   = (float*)(ws + 41307456);               // 82,313,216 B (fully overwritten)
  const size_t NEED_PART = 41307456ull + (size_t)8 * PSLICE * 4;

  (void)hipMemsetAsync(agg0, 0, 2560000 + 2560000 + 40000 + 16384 + 256, stream);

  prep_B<<<(KKTOT + 255) / 256, 256, 0, stream>>>(w2_1, b2_1, Bws);
  layer0_edge<<<512, 256, 0, stream>>>(node_ids, ei, ea, w1_0, b1_0, w2_0, b2_0, agg0, cnt);
  node0<<<(N_NODES * 64 + 255) / 256, 256, 0, stream>>>(node_ids, batch, agg0, cnt, root0, bias0, x1, pcnt);

  if (ws_size >= NEED_PART) {
    fused_edge_gemm<true><<<157 * 8, 256, 0, stream>>>(ei, ea, x1, w1_1, b1_1, Bws, P8);
    reduce_partials<<<(N_EDGES * 64) / 256, 256, 0, stream>>>(P8, ei, agg1);
  } else {
    fused_edge_gemm<false><<<157 * 8, 256, 0, stream>>>(ei, ea, x1, w1_1, b1_1, Bws, agg1);
  }

  node1_pool<<<(N_NODES + 3) / 4, 256, 0, stream>>>(batch, x1, agg1, cnt, root1, bias1, psum);
  classifier<<<N_GRAPH, 64, 0, stream>>>(psum, pcnt, wc1, bc1, wc2, bc2, out);
}